// Round 1
// baseline (13.018 us; speedup 1.0000x reference)
//
#include <hip/hip_runtime.h>
#include <hip/hip_bf16.h>

// Bruxism frame judgement: 512 scores -> (judgement, value).
// Single tiny dispatch; latency-bound by design.

#define N_CLASSES 512
#define N_COMBOS 13

__constant__ int   g_cls[N_COMBOS][3] = {
    {500,  41,   0},
    {369, 500,   0},
    {412, 431, 470},
    {127,  67, 103},
    {399, 403, 412},
    {410, 411, 398},
    {412, 410, 398},
    {435, 438, 449},
    {374, 436, 435},
    {372, 434, 469},
    {500, 439,  50},
    {399, 403, 410},
    {410, 398, 435},
};
__constant__ float g_min[N_COMBOS][3] = {
    {0.10f, 0.05f, 0.00f},
    {0.10f, 0.10f, 0.00f},
    {0.05f, 0.05f, 0.05f},
    {0.10f, 0.10f, 0.10f},
    {0.10f, 0.10f, 0.10f},
    {0.10f, 0.10f, 0.10f},
    {0.10f, 0.10f, 0.10f},
    {0.10f, 0.10f, 0.10f},
    {0.10f, 0.10f, 0.10f},
    {0.10f, 0.10f, 0.10f},
    {0.10f, 0.10f, 0.10f},
    {0.10f, 0.10f, 0.10f},
    {0.10f, 0.10f, 0.10f},
};
__constant__ float g_max[N_COMBOS][3] = {
    {0.8f, 0.5f, 1.0f},
    {0.5f, 0.5f, 1.0f},
    {0.4f, 0.4f, 0.4f},
    {0.8f, 0.7f, 0.6f},
    {0.9f, 0.8f, 0.7f},
    {0.9f, 0.8f, 0.7f},
    {0.8f, 0.7f, 0.6f},
    {0.9f, 0.8f, 0.7f},
    {0.9f, 0.8f, 0.7f},
    {0.9f, 0.8f, 0.7f},
    {0.8f, 0.7f, 0.6f},
    {0.9f, 0.8f, 0.7f},
    {0.9f, 0.8f, 0.7f},
};
__constant__ float g_brux[N_COMBOS] = {
    2.94f, 1.76f, 1.76f, 1.47f, 0.29f, 0.88f, 0.01f,
    0.29f, 0.29f, 0.01f, 0.29f, 0.01f, 0.01f
};
__constant__ int g_nonbrux[3] = {38, 42, 0};

__global__ __launch_bounds__(512)
void bruxism_judge_kernel(const float* __restrict__ score, float* __restrict__ out) {
    __shared__ float s[N_CLASSES];
    __shared__ int   cnt[3];   // rank counts for the 3 non-brux classes

    const int t = threadIdx.x;
    s[t] = score[t];
    if (t < 3) cnt[t] = 0;
    __syncthreads();

    const float v = s[t];

    // Rank of each non-brux class value with lax.top_k's stable tie-break:
    // rank(c) = #{j : s[j] > s[c]}  +  #{j : s[j] == s[c] && j < c}
    // class c is in the top-10 iff rank(c) < 10.
    #pragma unroll
    for (int k = 0; k < 3; ++k) {
        const int   c  = g_nonbrux[k];
        const float sc = s[c];
        const bool beats = (v > sc) || ((v == sc) && (t < c));
        const unsigned long long m = __ballot(beats);
        if ((t & 63) == 0) {
            atomicAdd(&cnt[k], __popcll(m));
        }
    }
    __syncthreads();

    if (t == 0) {
        const bool has_non_brux = (cnt[0] < 10) || (cnt[1] < 10) || (cnt[2] < 10);

        // First passing combo (argmax of combo_pass); 0 if none pass.
        bool any_pass = false;
        int  first    = 0;
        #pragma unroll
        for (int i = N_COMBOS - 1; i >= 0; --i) {
            bool pass = true;
            #pragma unroll
            for (int j = 0; j < 3; ++j) {
                const float val = s[g_cls[i][j]];
                pass = pass && (val >= g_min[i][j]) && (val <= g_max[i][j]);
            }
            if (pass) { any_pass = true; first = i; }
        }

        const bool judgement = any_pass && !has_non_brux;
        // jnp.round is round-half-to-even -> rintf (default FE_TONEAREST).
        const float value = judgement ? (rintf(g_brux[first] * 100.0f) * 0.01f)
                                      : 0.0f;
        out[0] = judgement ? 1.0f : 0.0f;
        out[1] = value;
    }
}

extern "C" void kernel_launch(void* const* d_in, const int* in_sizes, int n_in,
                              void* d_out, int out_size, void* d_ws, size_t ws_size,
                              hipStream_t stream) {
    const float* score = (const float*)d_in[0];
    float* out = (float*)d_out;
    bruxism_judge_kernel<<<1, 512, 0, stream>>>(score, out);
}

// Round 2
// 9.737 us; speedup vs baseline: 1.3370x; 1.3370x over previous
//
#include <hip/hip_runtime.h>
#include <hip/hip_bf16.h>

// Bruxism frame judgement: 512 scores -> (judgement, value).
// Single-wave (64-lane) kernel: 2 coalesced float4 loads, shuffle-based
// rank reduction, no barriers, no atomics. Latency-bound by design.

#define N_COMBOS 13

__global__ __launch_bounds__(64)
void bruxism_judge_kernel(const float* __restrict__ score, float* __restrict__ out) {
    __shared__ float s_lds[512];

    const int t = threadIdx.x;  // 0..63

    // Lane t holds elems [4t..4t+3] and [256+4t..256+4t+3].
    const float4 a = reinterpret_cast<const float4*>(score)[t];
    const float4 b = reinterpret_cast<const float4*>(score)[64 + t];

    // Stash to LDS for the arbitrary-index combo checks below. Single wave:
    // program order guarantees all ds_writes precede the ds_reads; the
    // compiler inserts the lgkmcnt wait. No __syncthreads needed.
    reinterpret_cast<float4*>(s_lds)[t]      = a;
    reinterpret_cast<float4*>(s_lds)[64 + t] = b;

    const float v[8]  = {a.x, a.y, a.z, a.w, b.x, b.y, b.z, b.w};

    // Non-brux classes: 38 = lane 9 elem .z, 42 = lane 10 elem .z, 0 = lane 0 elem .x
    const float s38 = __shfl(a.z, 9);
    const float s42 = __shfl(a.z, 10);
    const float s0  = __shfl(a.x, 0);

    // rank(c) = #{j : s[j] > s[c]} + #{j : s[j] == s[c] && j < c}   (lax.top_k
    // stable tie-break). Class c in top-10 iff rank(c) < 10.
    // Pack the three counts into one int: 10 bits each (max 511).
    int packed = 0;
    #pragma unroll
    for (int e = 0; e < 8; ++e) {
        const float x = v[e];
        const int   j = (e < 4) ? (4 * t + e) : (256 + 4 * t + (e - 4));
        packed += ((x > s38) || ((x == s38) && (j < 38))) ? (1 << 0)  : 0;
        packed += ((x > s42) || ((x == s42) && (j < 42))) ? (1 << 10) : 0;
        packed += ( (x > s0)                            ) ? (1 << 20) : 0; // j<0 impossible
    }
    #pragma unroll
    for (int off = 32; off >= 1; off >>= 1) packed += __shfl_xor(packed, off);

    const int cnt38 = (packed >> 0)  & 1023;
    const int cnt42 = (packed >> 10) & 1023;
    const int cnt0  = (packed >> 20) & 1023;
    const bool has_non_brux = (cnt38 < 10) || (cnt42 < 10) || (cnt0 < 10);

    // Combo range checks — constexpr tables fold to immediate LDS offsets.
    constexpr int cls[N_COMBOS][3] = {
        {500,  41,   0}, {369, 500,   0}, {412, 431, 470}, {127,  67, 103},
        {399, 403, 412}, {410, 411, 398}, {412, 410, 398}, {435, 438, 449},
        {374, 436, 435}, {372, 434, 469}, {500, 439,  50}, {399, 403, 410},
        {410, 398, 435},
    };
    constexpr float cmin[N_COMBOS][3] = {
        {0.10f, 0.05f, 0.00f}, {0.10f, 0.10f, 0.00f}, {0.05f, 0.05f, 0.05f},
        {0.10f, 0.10f, 0.10f}, {0.10f, 0.10f, 0.10f}, {0.10f, 0.10f, 0.10f},
        {0.10f, 0.10f, 0.10f}, {0.10f, 0.10f, 0.10f}, {0.10f, 0.10f, 0.10f},
        {0.10f, 0.10f, 0.10f}, {0.10f, 0.10f, 0.10f}, {0.10f, 0.10f, 0.10f},
        {0.10f, 0.10f, 0.10f},
    };
    constexpr float cmax[N_COMBOS][3] = {
        {0.8f, 0.5f, 1.0f}, {0.5f, 0.5f, 1.0f}, {0.4f, 0.4f, 0.4f},
        {0.8f, 0.7f, 0.6f}, {0.9f, 0.8f, 0.7f}, {0.9f, 0.8f, 0.7f},
        {0.8f, 0.7f, 0.6f}, {0.9f, 0.8f, 0.7f}, {0.9f, 0.8f, 0.7f},
        {0.9f, 0.8f, 0.7f}, {0.8f, 0.7f, 0.6f}, {0.9f, 0.8f, 0.7f},
        {0.9f, 0.8f, 0.7f},
    };
    constexpr float brux[N_COMBOS] = {
        2.94f, 1.76f, 1.76f, 1.47f, 0.29f, 0.88f, 0.01f,
        0.29f, 0.29f, 0.01f, 0.29f, 0.01f, 0.01f
    };

    bool any_pass = false;
    int  first    = 0;
    #pragma unroll
    for (int i = N_COMBOS - 1; i >= 0; --i) {
        bool pass = true;
        #pragma unroll
        for (int j = 0; j < 3; ++j) {
            const float val = s_lds[cls[i][j]];
            pass = pass && (val >= cmin[i][j]) && (val <= cmax[i][j]);
        }
        if (pass) { any_pass = true; first = i; }
    }

    if (t == 0) {
        const bool judgement = any_pass && !has_non_brux;
        float bs = brux[0];
        #pragma unroll
        for (int i = 1; i < N_COMBOS; ++i) bs = (first == i) ? brux[i] : bs;
        // jnp.round is round-half-to-even -> rintf; divide (not *0.01) to
        // match the reference's f32 op sequence exactly.
        const float value = judgement ? (rintf(bs * 100.0f) / 100.0f) : 0.0f;
        float2 o = make_float2(judgement ? 1.0f : 0.0f, value);
        *reinterpret_cast<float2*>(out) = o;
    }
}

extern "C" void kernel_launch(void* const* d_in, const int* in_sizes, int n_in,
                              void* d_out, int out_size, void* d_ws, size_t ws_size,
                              hipStream_t stream) {
    const float* score = (const float*)d_in[0];
    float* out = (float*)d_out;
    bruxism_judge_kernel<<<1, 64, 0, stream>>>(score, out);
}